// Round 8
// baseline (283.241 us; speedup 1.0000x reference)
//
#include <hip/hip_runtime.h>

// ---- problem constants (from reference) ----
#define SEQ      10688      // IMG_LEN + TEXT_LEN
#define IMG_LEN  10368      // 18*24*24
#define TEXT_LEN 320
#define DH       128
#define NHEADS   4
#define SLAB     3456       // 6*24*24 tokens per time-slab
#define KVC      64         // kv chunk rows
#define QT       128        // q rows per block (4 waves x 32)
#define NIT      81         // image q-tiles per head
#define NTT      3          // text q-tiles per head (last tile half-valid)
#define NCH_TXT  167        // SEQ/KVC
#define NCH_IMG  59         // 54 slab chunks + 5 text chunks
#define SCALEL2E 0.12751744518924593f   // (1/sqrt(128)) * log2(e)
#define DEFER_THR 8.0f      // defer-max rescale threshold (T13)

typedef __bf16 bf16x8 __attribute__((ext_vector_type(8)));
typedef __bf16 bf16x4 __attribute__((ext_vector_type(4)));
typedef float  f32x4  __attribute__((ext_vector_type(4)));

__device__ __forceinline__ unsigned pk2bf(float a, float b) {
    union { __bf16 h[2]; unsigned u; } t;
    t.h[0] = (__bf16)a; t.h[1] = (__bf16)b;
    return t.u;
}

__device__ __forceinline__ void split_range(int total, int nsplit, int s, int& c0, int& n) {
    const int q = total / nsplit, r = total % nsplit;
    if (s < r) { c0 = s * (q + 1); n = q + 1; }
    else       { c0 = r * (q + 1) + (s - r) * q; n = q; }
}

template<int TS, int IS> struct Geo {
    static constexpr int NTXTB = NHEADS * NTT * TS;
    static constexpr int NIMGB = NHEADS * NIT * IS;
    static constexpr int NPID  = NTXTB + NIMGB;
    static constexpr size_t WS_FLOATS = (size_t)NPID * (QT * DH + QT * 2);
};

// NOTE: NO min-waves clamp! (256,4)->64 VGPR and (256,2)->128 VGPR both caused
// catastrophic scratch spills (rounds 3/5). Unconstrained: 120 VGPR, 0 spill,
// 4 waves/SIMD; 32KB LDS -> cap 4 blocks/CU. Grid must oversubscribe that cap.
template<int TS, int IS, bool SPLIT>
__global__ __launch_bounds__(256) void sta_attn(const float* __restrict__ Qg,
                                                const float* __restrict__ Kg,
                                                const float* __restrict__ Vg,
                                                float* __restrict__ Og,
                                                float* __restrict__ Opart,
                                                float* __restrict__ Ml) {
    using G = Geo<TS, IS>;
    // K: [kv][d] bf16, 8-elem-granule XOR swizzle key (kv&7).
    // V^T: [d][kv] bf16, 8-elem-granule XOR swizzle key ((d>>1)&7).
    __shared__ __align__(16) unsigned short LK[KVC * DH];     // 16KB
    __shared__ __align__(16) unsigned short VT[DH * KVC];     // 16KB

    const int tid  = threadIdx.x;
    const int lane = tid & 63;
    const int wv   = tid >> 6;
    const int q    = lane & 15;       // MFMA col position (q for QK/PV outputs)
    const int g    = lane >> 4;       // lane group 0..3
    const int sw16 = (q & 7) << 4;    // K-read swizzle key (bytes)
    const int qk2  = q >> 1;          // V-read swizzle key
    const int gh   = g >> 1;
    const int gb   = (g & 1) * 8;     // byte sub-offset within V granule
    const int d2   = tid & 63;        // V staging: d-pair index
    const int kvb  = tid >> 6;        // V staging: kv block of 16

    int b = blockIdx.x;
    int head, qbase, nch, ch0, kvb0, pid = 0;
    bool isText;
    if (b < G::NTXTB) {                        // text splits first (longest poles)
        int tb = b / TS, s = b % TS;
        head = tb / NTT; qbase = IMG_LEN + (tb % NTT) * QT;
        isText = true; kvb0 = 0;
        split_range(NCH_TXT, TS, s, ch0, nch);
        pid = b;
    } else {
        int bb = b - G::NTXTB; int tile = bb / IS, s = bb % IS;
        head = tile / NIT; qbase = (tile % NIT) * QT;
        isText = false; kvb0 = (qbase / SLAB) * SLAB;
        split_range(NCH_IMG, IS, s, ch0, nch);
        pid = G::NTXTB + bb;
    }

    const size_t hoff = (size_t)head * SEQ * DH;
    const float* Qh = Qg + hoff;
    const float* Kh = Kg + hoff;
    const float* Vh = Vg + hoff;

    // ---- Q fragments for 2 q-subtiles (B-operand layout), scale folded ----
    bf16x8 qf[2][4];
    #pragma unroll
    for (int n = 0; n < 2; ++n) {
        int qr = qbase + wv * 32 + n * 16 + q;
        if (qr > SEQ - 1) qr = SEQ - 1;        // text tail: clamp (discarded at store)
        const float* qp = Qh + (size_t)qr * DH;
        #pragma unroll
        for (int c = 0; c < 4; ++c) {
            float4 a = *(const float4*)(qp + c * 32 + g * 8);
            float4 d = *(const float4*)(qp + c * 32 + g * 8 + 4);
            union { unsigned u[4]; bf16x8 v; } t;
            t.u[0] = pk2bf(a.x * SCALEL2E, a.y * SCALEL2E);
            t.u[1] = pk2bf(a.z * SCALEL2E, a.w * SCALEL2E);
            t.u[2] = pk2bf(d.x * SCALEL2E, d.y * SCALEL2E);
            t.u[3] = pk2bf(d.z * SCALEL2E, d.w * SCALEL2E);
            qf[n][c] = t.v;
        }
    }

    f32x4 o[2][8];
    #pragma unroll
    for (int n = 0; n < 2; ++n)
        #pragma unroll
        for (int dt = 0; dt < 8; ++dt) o[n][dt] = f32x4{0.f, 0.f, 0.f, 0.f};
    float mrun[2] = {-INFINITY, -INFINITY};
    float lsum[2] = {0.f, 0.f};

    auto kvaddr = [&](int gch) -> int {
        return isText ? gch * KVC
                      : (gch < 54 ? kvb0 + gch * KVC : IMG_LEN + (gch - 54) * KVC);
    };

    // Inline staging, transients only (no persistent staging registers).
    #define STAGE(KB)                                                            \
        {   const int _kb = (KB);                                                \
            float4 kf4[8];                                                       \
            _Pragma("unroll")                                                    \
            for (int s = 0; s < 8; ++s) {                                        \
                int idx = tid + (s << 8);                                        \
                kf4[s] = *(const float4*)(Kh + (size_t)(_kb + (idx >> 5)) * DH   \
                                          + (idx & 31) * 4);                     \
            }                                                                    \
            const float* vpp = Vh + (size_t)(_kb + kvb * 16) * DH + d2 * 2;      \
            float2 va[8];                                                        \
            _Pragma("unroll")                                                    \
            for (int j = 0; j < 8; ++j) va[j] = *(const float2*)(vpp + j * DH);  \
            _Pragma("unroll")                                                    \
            for (int s = 0; s < 8; ++s) {                                        \
                int idx = tid + (s << 8);                                        \
                int kv = idx >> 5, dq = idx & 31;                                \
                uint2 u; u.x = pk2bf(kf4[s].x, kf4[s].y);                        \
                         u.y = pk2bf(kf4[s].z, kf4[s].w);                        \
                *(uint2*)&LK[kv * DH + ((dq * 4) ^ ((kv & 7) << 3))] = u;        \
            }                                                                    \
            float2 vb[8];                                                        \
            _Pragma("unroll")                                                    \
            for (int j = 0; j < 8; ++j) vb[j] = *(const float2*)(vpp + (8 + j) * DH); \
            const int g0 = ((kvb * 2 + 0) ^ (d2 & 7)) * 8;                       \
            const int g1 = ((kvb * 2 + 1) ^ (d2 & 7)) * 8;                       \
            _Pragma("unroll")                                                    \
            for (int h = 0; h < 2; ++h) {                                        \
                const int d = d2 * 2 + h;                                        \
                uint4 u0, u1;                                                    \
                u0.x = pk2bf(h ? va[0].y : va[0].x, h ? va[1].y : va[1].x);      \
                u0.y = pk2bf(h ? va[2].y : va[2].x, h ? va[3].y : va[3].x);      \
                u0.z = pk2bf(h ? va[4].y : va[4].x, h ? va[5].y : va[5].x);      \
                u0.w = pk2bf(h ? va[6].y : va[6].x, h ? va[7].y : va[7].x);      \
                u1.x = pk2bf(h ? vb[0].y : vb[0].x, h ? vb[1].y : vb[1].x);      \
                u1.y = pk2bf(h ? vb[2].y : vb[2].x, h ? vb[3].y : vb[3].x);      \
                u1.z = pk2bf(h ? vb[4].y : vb[4].x, h ? vb[5].y : vb[5].x);      \
                u1.w = pk2bf(h ? vb[6].y : vb[6].x, h ? vb[7].y : vb[7].x);      \
                *(uint4*)&VT[d * KVC + g0] = u0;                                 \
                *(uint4*)&VT[d * KVC + g1] = u1;                                 \
            }                                                                    \
        }

    STAGE(kvaddr(ch0));
    __syncthreads();

    for (int ch = 0; ch < nch; ++ch) {
        // ---- S^T = K * Q^T : st[n][kt][r] = S[kv=kt*16+g*4+r][q=n*16+q'] ----
        f32x4 st[2][4];
        #pragma unroll
        for (int n = 0; n < 2; ++n)
            #pragma unroll
            for (int kt = 0; kt < 4; ++kt) st[n][kt] = f32x4{0.f, 0.f, 0.f, 0.f};
        __builtin_amdgcn_s_setprio(1);
        #pragma unroll
        for (int c = 0; c < 4; ++c) {
            #pragma unroll
            for (int kt = 0; kt < 4; ++kt) {
                bf16x8 kf = *(const bf16x8*)((const char*)LK
                              + (kt*16 + q) * 256 + ((c * 64 + g * 16) ^ sw16));
                st[0][kt] = __builtin_amdgcn_mfma_f32_16x16x32_bf16(kf, qf[0][c], st[0][kt], 0, 0, 0);
                st[1][kt] = __builtin_amdgcn_mfma_f32_16x16x32_bf16(kf, qf[1][c], st[1][kt], 0, 0, 0);
            }
        }
        __builtin_amdgcn_s_setprio(0);

        // ---- online softmax (log2 domain), defer-max ----
        float cm[2];
        #pragma unroll
        for (int n = 0; n < 2; ++n) {
            float c0 = -INFINITY;
            #pragma unroll
            for (int kt = 0; kt < 4; ++kt)
                #pragma unroll
                for (int r = 0; r < 4; ++r) c0 = fmaxf(c0, st[n][kt][r]);
            c0 = fmaxf(c0, __shfl_xor(c0, 16));
            c0 = fmaxf(c0, __shfl_xor(c0, 32));
            cm[n] = c0;
        }
        if (!__all((cm[0] <= mrun[0] + DEFER_THR) && (cm[1] <= mrun[1] + DEFER_THR))) {
            #pragma unroll
            for (int n = 0; n < 2; ++n) {
                float mnew = fmaxf(mrun[n], cm[n]);
                float sc = exp2f(mrun[n] - mnew);
                lsum[n] *= sc;
                #pragma unroll
                for (int dt = 0; dt < 8; ++dt) o[n][dt] *= sc;
                mrun[n] = mnew;
            }
        }

        // P in bf16: the K=16 B-fragment (k=g*4+j, col=q) IS the st layout ->
        // feeds PV directly, no LDS/shuffle redistribution.
        bf16x4 pkv[2][4];
        #pragma unroll
        for (int n = 0; n < 2; ++n) {
            float ps = 0.f;
            #pragma unroll
            for (int kt = 0; kt < 4; ++kt) {
                float p0 = exp2f(st[n][kt][0] - mrun[n]);
                float p1 = exp2f(st[n][kt][1] - mrun[n]);
                float p2 = exp2f(st[n][kt][2] - mrun[n]);
                float p3 = exp2f(st[n][kt][3] - mrun[n]);
                ps += (p0 + p1) + (p2 + p3);
                union { unsigned u[2]; bf16x4 v; } t;
                t.u[0] = pk2bf(p0, p1);
                t.u[1] = pk2bf(p2, p3);
                pkv[n][kt] = t.v;
            }
            ps += __shfl_xor(ps, 16);
            ps += __shfl_xor(ps, 32);
            lsum[n] += ps;
        }

        // ---- O^T += V^T * P^T via K=16 MFMA, A=V^T from LDS (b64), B=pkv regs ----
        __builtin_amdgcn_s_setprio(1);
        #pragma unroll
        for (int kt = 0; kt < 4; ++kt) {
            bf16x4 vfr[8];
            #pragma unroll
            for (int dt = 0; dt < 8; ++dt) {
                const int d = dt * 16 + q;
                vfr[dt] = *(const bf16x4*)((const char*)VT
                            + d * 128 + (((kt * 2 + gh) ^ qk2) << 4) + gb);
            }
            #pragma unroll
            for (int dt = 0; dt < 8; ++dt) {
                asm("v_mfma_f32_16x16x16_bf16 %0, %1, %2, %0"
                    : "+v"(o[0][dt]) : "v"(vfr[dt]), "v"(pkv[0][kt]));
                asm("v_mfma_f32_16x16x16_bf16 %0, %1, %2, %0"
                    : "+v"(o[1][dt]) : "v"(vfr[dt]), "v"(pkv[1][kt]));
            }
        }
        __builtin_amdgcn_s_setprio(0);

        if (ch + 1 < nch) {
            __syncthreads();           // all waves done reading LDS
            STAGE(kvaddr(ch0 + ch + 1));
            __syncthreads();
        }
    }

    // hazard insurance: asm MFMA writes o[], epilogue VALU reads it soon after
    asm volatile("s_nop 7\n\ts_nop 7");

    if constexpr (SPLIT) {
        float* opb = Opart + (size_t)pid * (QT * DH);
        #pragma unroll
        for (int n = 0; n < 2; ++n) {
            const int row = wv * 32 + n * 16 + q;
            float* op = opb + row * DH;
            #pragma unroll
            for (int dt = 0; dt < 8; ++dt) {
                float4 v;
                v.x = o[n][dt][0]; v.y = o[n][dt][1]; v.z = o[n][dt][2]; v.w = o[n][dt][3];
                *(float4*)(op + dt * 16 + g * 4) = v;
            }
            if (g == 0) {
                Ml[(size_t)pid * (QT * 2) + row * 2]     = mrun[n];
                Ml[(size_t)pid * (QT * 2) + row * 2 + 1] = lsum[n];
            }
        }
    } else {
        #pragma unroll
        for (int n = 0; n < 2; ++n) {
            const int qrow = qbase + wv * 32 + n * 16 + q;
            if (qrow >= SEQ) continue;
            const float inv = 1.f / (lsum[n] + 64.f * exp2f(-mrun[n]));
            float* op = Og + hoff + (size_t)qrow * DH;
            #pragma unroll
            for (int dt = 0; dt < 8; ++dt) {
                float4 v;
                v.x = o[n][dt][0] * inv; v.y = o[n][dt][1] * inv;
                v.z = o[n][dt][2] * inv; v.w = o[n][dt][3] * inv;
                *(float4*)(op + dt * 16 + g * 4) = v;
            }
        }
    }
    #undef STAGE
}

// compile-time-S merge body (runtime-indexed local arrays would go to scratch)
template<int S>
__device__ __forceinline__ void merge_body(const float* __restrict__ Opart,
                                           const float* __restrict__ Ml,
                                           float* __restrict__ Og,
                                           int head, int qbase, int pbase,
                                           int row, int c0) {
    if (qbase + row >= SEQ) return;       // text tail
    float w[S], lv[S];
    float m = -INFINITY;
    #pragma unroll
    for (int s = 0; s < S; ++s) {
        w[s]  = Ml[(size_t)(pbase + s) * (QT * 2) + row * 2];
        lv[s] = Ml[(size_t)(pbase + s) * (QT * 2) + row * 2 + 1];
        m = fmaxf(m, w[s]);
    }
    float L = 64.f * exp2f(-m);           // 64 zero-pad keys (log2 domain)
    #pragma unroll
    for (int s = 0; s < S; ++s) { w[s] = exp2f(w[s] - m); L += w[s] * lv[s]; }
    const float inv = 1.f / L;

    float* op = Og + (size_t)head * SEQ * DH + (size_t)(qbase + row) * DH + c0;
    #pragma unroll
    for (int j = 0; j < 16; ++j) {
        float4 acc = make_float4(0.f, 0.f, 0.f, 0.f);
        #pragma unroll
        for (int s = 0; s < S; ++s) {
            const float4 p = *(const float4*)(Opart + (size_t)(pbase + s) * (QT * DH)
                                              + row * DH + c0 + j * 4);
            acc.x += w[s] * p.x; acc.y += w[s] * p.y;
            acc.z += w[s] * p.z; acc.w += w[s] * p.w;
        }
        float4 v; v.x = acc.x * inv; v.y = acc.y * inv; v.z = acc.z * inv; v.w = acc.w * inv;
        *(float4*)(op + j * 4) = v;
    }
}

template<int TS, int IS>
__global__ __launch_bounds__(256) void sta_merge(const float* __restrict__ Opart,
                                                 const float* __restrict__ Ml,
                                                 float* __restrict__ Og) {
    const int b = blockIdx.x;             // original q-tile
    const int t = threadIdx.x;
    const int row = t >> 1;               // 0..127
    const int c0  = (t & 1) * 64;
    if (b < NHEADS * NTT) {
        merge_body<TS>(Opart, Ml, Og, b / NTT, IMG_LEN + (b % NTT) * QT,
                       b * TS, row, c0);
    } else {
        const int tile = b - NHEADS * NTT;
        merge_body<IS>(Opart, Ml, Og, tile / NIT, (tile % NIT) * QT,
                       NHEADS * NTT * TS + tile * IS, row, c0);
    }
}

extern "C" void kernel_launch(void* const* d_in, const int* in_sizes, int n_in,
                              void* d_out, int out_size, void* d_ws, size_t ws_size,
                              hipStream_t stream) {
    const float* Qg = (const float*)d_in[0];
    const float* Kg = (const float*)d_in[1];
    const float* Vg = (const float*)d_in[2];
    float* Og = (float*)d_out;
    float* ws = (float*)d_ws;

    if (ws_size >= Geo<8, 4>::WS_FLOATS * sizeof(float)) {
        float* Opart = ws;
        float* Ml    = Opart + (size_t)Geo<8, 4>::NPID * QT * DH;
        hipLaunchKernelGGL((sta_attn<8, 4, true>), dim3(Geo<8, 4>::NPID), dim3(256), 0, stream,
                           Qg, Kg, Vg, Og, Opart, Ml);
        hipLaunchKernelGGL((sta_merge<8, 4>), dim3(NHEADS * (NTT + NIT)), dim3(256), 0, stream,
                           Opart, Ml, Og);
    } else if (ws_size >= Geo<4, 2>::WS_FLOATS * sizeof(float)) {
        float* Opart = ws;
        float* Ml    = Opart + (size_t)Geo<4, 2>::NPID * QT * DH;
        hipLaunchKernelGGL((sta_attn<4, 2, true>), dim3(Geo<4, 2>::NPID), dim3(256), 0, stream,
                           Qg, Kg, Vg, Og, Opart, Ml);
        hipLaunchKernelGGL((sta_merge<4, 2>), dim3(NHEADS * (NTT + NIT)), dim3(256), 0, stream,
                           Opart, Ml, Og);
    } else {
        hipLaunchKernelGGL((sta_attn<1, 1, false>), dim3(Geo<1, 1>::NPID), dim3(256), 0, stream,
                           Qg, Kg, Vg, Og, (float*)nullptr, (float*)nullptr);
    }
}

// Round 9
// 222.327 us; speedup vs baseline: 1.2740x; 1.2740x over previous
//
#include <hip/hip_runtime.h>

// ---- problem constants (from reference) ----
#define SEQ      10688      // IMG_LEN + TEXT_LEN
#define IMG_LEN  10368      // 18*24*24
#define TEXT_LEN 320
#define DH       128
#define NHEADS   4
#define SLAB     3456       // 6*24*24 tokens per time-slab
#define KVC      32         // kv chunk rows (32: staging fits 32 VGPRs -> T14 viable at 3 waves/SIMD)
#define QT       128        // q rows per block (4 waves x 32)
#define NIT      81         // image q-tiles per head
#define NTT      3          // text q-tiles per head (last tile half-valid)
#define NCH_TXT  334        // SEQ/KVC
#define NCH_IMG  118        // 108 slab chunks + 10 text chunks
#define SCALEL2E 0.12751744518924593f   // (1/sqrt(128)) * log2(e)
#define DEFER_THR 8.0f      // defer-max rescale threshold (T13)

typedef __bf16 bf16x8 __attribute__((ext_vector_type(8)));
typedef __bf16 bf16x4 __attribute__((ext_vector_type(4)));
typedef float  f32x4  __attribute__((ext_vector_type(4)));

__device__ __forceinline__ unsigned pk2bf(float a, float b) {
    union { __bf16 h[2]; unsigned u; } t;
    t.h[0] = (__bf16)a; t.h[1] = (__bf16)b;
    return t.u;
}

__device__ __forceinline__ void split_range(int total, int nsplit, int s, int& c0, int& n) {
    const int q = total / nsplit, r = total % nsplit;
    if (s < r) { c0 = s * (q + 1); n = q + 1; }
    else       { c0 = r * (q + 1) + (s - r) * q; n = q; }
}

template<int TS, int IS> struct Geo {
    static constexpr int NTXTB = NHEADS * NTT * TS;
    static constexpr int NIMGB = NHEADS * NIT * IS;
    static constexpr int NPID  = NTXTB + NIMGB;
    static constexpr size_t WS_FLOATS = (size_t)NPID * (QT * DH + QT * 2);
};

// NOTE: NO min-waves clamp! (256,4)->64 VGPR and (256,2)->128 VGPR both caused
// catastrophic scratch spills (rounds 3/5). Target <=168 VGPR (3 waves/SIMD).
// T14: K/V loads for chunk n+1 issue at top of chunk n (32 staging VGPRs),
// LDS write-back after the barrier -- HBM latency hides under QK+softmax+PV.
template<int TS, int IS, bool SPLIT>
__global__ __launch_bounds__(256) void sta_attn(const float* __restrict__ Qg,
                                                const float* __restrict__ Kg,
                                                const float* __restrict__ Vg,
                                                float* __restrict__ Og,
                                                float* __restrict__ Opart,
                                                float* __restrict__ Ml) {
    using G = Geo<TS, IS>;
    // K: [kv][d] bf16 (32x128, 8KB), 8-elem-granule XOR swizzle key (kv&7).
    // V^T: [d][kv] bf16 (128x32, 8KB), 16B-granule XOR swizzle key ((d>>1)&3).
    __shared__ __align__(16) unsigned short LK[KVC * DH];
    __shared__ __align__(16) unsigned short VT[DH * KVC];

    const int tid  = threadIdx.x;
    const int lane = tid & 63;
    const int wv   = tid >> 6;
    const int q    = lane & 15;       // MFMA col position (q for QK/PV outputs)
    const int g    = lane >> 4;       // lane group 0..3
    const int sw16 = (q & 7) << 4;    // K-read swizzle key (bytes)
    const int vkey = (q >> 1) & 3;    // V-read swizzle key (granule)
    const int gh   = g >> 1;
    const int gb   = (g & 1) * 8;     // byte sub-offset within V granule
    const int d2   = tid & 63;        // V staging: d-pair index (0..63)
    const int kvb  = tid >> 6;        // V staging: kv block of 8 (0..3)

    int b = blockIdx.x;
    int head, qbase, nch, ch0, kvb0, pid = 0;
    bool isText;
    if (b < G::NTXTB) {                        // text splits first (longest poles)
        int tb = b / TS, s = b % TS;
        head = tb / NTT; qbase = IMG_LEN + (tb % NTT) * QT;
        isText = true; kvb0 = 0;
        split_range(NCH_TXT, TS, s, ch0, nch);
        pid = b;
    } else {
        int bb = b - G::NTXTB; int tile = bb / IS, s = bb % IS;
        head = tile / NIT; qbase = (tile % NIT) * QT;
        isText = false; kvb0 = (qbase / SLAB) * SLAB;
        split_range(NCH_IMG, IS, s, ch0, nch);
        pid = G::NTXTB + bb;
    }

    const size_t hoff = (size_t)head * SEQ * DH;
    const float* Qh = Qg + hoff;
    const float* Kh = Kg + hoff;
    const float* Vh = Vg + hoff;

    // ---- Q fragments for 2 q-subtiles (B-operand layout), scale folded ----
    bf16x8 qf[2][4];
    #pragma unroll
    for (int n = 0; n < 2; ++n) {
        int qr = qbase + wv * 32 + n * 16 + q;
        if (qr > SEQ - 1) qr = SEQ - 1;        // text tail: clamp (discarded at store)
        const float* qp = Qh + (size_t)qr * DH;
        #pragma unroll
        for (int c = 0; c < 4; ++c) {
            float4 a = *(const float4*)(qp + c * 32 + g * 8);
            float4 d = *(const float4*)(qp + c * 32 + g * 8 + 4);
            union { unsigned u[4]; bf16x8 v; } t;
            t.u[0] = pk2bf(a.x * SCALEL2E, a.y * SCALEL2E);
            t.u[1] = pk2bf(a.z * SCALEL2E, a.w * SCALEL2E);
            t.u[2] = pk2bf(d.x * SCALEL2E, d.y * SCALEL2E);
            t.u[3] = pk2bf(d.z * SCALEL2E, d.w * SCALEL2E);
            qf[n][c] = t.v;
        }
    }

    f32x4 o[2][8];
    #pragma unroll
    for (int n = 0; n < 2; ++n)
        #pragma unroll
        for (int dt = 0; dt < 8; ++dt) o[n][dt] = f32x4{0.f, 0.f, 0.f, 0.f};
    float mrun[2] = {-INFINITY, -INFINITY};
    float lsum[2] = {0.f, 0.f};

    // persistent staging registers (32 VGPR): K 4xfloat4, V 8xfloat2
    float4 kreg[4];
    float2 vreg[8];

    auto kvaddr = [&](int gch) -> int {
        return isText ? gch * KVC
                      : (gch < 108 ? kvb0 + gch * KVC : IMG_LEN + (gch - 108) * KVC);
    };

    // issue-early: global loads only (latency flies under compute)
    #define STAGE_LOAD(KB)                                                       \
        {   const int _kb = (KB);                                                \
            _Pragma("unroll")                                                    \
            for (int s = 0; s < 4; ++s) {                                        \
                int idx = tid + (s << 8);                                        \
                kreg[s] = *(const float4*)(Kh + (size_t)(_kb + (idx >> 5)) * DH  \
                                           + (idx & 31) * 4);                    \
            }                                                                    \
            const float* vpp = Vh + (size_t)(_kb + kvb * 8) * DH + d2 * 2;       \
            _Pragma("unroll")                                                    \
            for (int j = 0; j < 8; ++j) vreg[j] = *(const float2*)(vpp + j * DH);\
        }

    // write-late: cvt + LDS writes (vmcnt satisfied by the time we get here)
    #define STAGE_WRITE()                                                        \
        {   _Pragma("unroll")                                                    \
            for (int s = 0; s < 4; ++s) {                                        \
                int idx = tid + (s << 8);                                        \
                int kv = idx >> 5, dq = idx & 31;                                \
                uint2 u; u.x = pk2bf(kreg[s].x, kreg[s].y);                      \
                         u.y = pk2bf(kreg[s].z, kreg[s].w);                      \
                *(uint2*)&LK[kv * DH + ((dq * 4) ^ ((kv & 7) << 3))] = u;        \
            }                                                                    \
            _Pragma("unroll")                                                    \
            for (int h = 0; h < 2; ++h) {                                        \
                const int d = d2 * 2 + h;                                        \
                uint4 u;                                                         \
                u.x = pk2bf(h ? vreg[0].y : vreg[0].x, h ? vreg[1].y : vreg[1].x);\
                u.y = pk2bf(h ? vreg[2].y : vreg[2].x, h ? vreg[3].y : vreg[3].x);\
                u.z = pk2bf(h ? vreg[4].y : vreg[4].x, h ? vreg[5].y : vreg[5].x);\
                u.w = pk2bf(h ? vreg[6].y : vreg[6].x, h ? vreg[7].y : vreg[7].x);\
                *(uint4*)&VT[d * KVC + ((kvb ^ (d2 & 3)) * 8)] = u;              \
            }                                                                    \
        }

    STAGE_LOAD(kvaddr(ch0));
    STAGE_WRITE();
    __syncthreads();

    for (int ch = 0; ch < nch; ++ch) {
        // T14: issue next chunk's global loads NOW; they retire under compute
        if (ch + 1 < nch) STAGE_LOAD(kvaddr(ch0 + ch + 1));

        // ---- S^T = K * Q^T : st[n][kt][r] = S[kv=kt*16+g*4+r][q=n*16+q'] ----
        f32x4 st[2][2];
        #pragma unroll
        for (int n = 0; n < 2; ++n)
            #pragma unroll
            for (int kt = 0; kt < 2; ++kt) st[n][kt] = f32x4{0.f, 0.f, 0.f, 0.f};
        __builtin_amdgcn_s_setprio(1);
        #pragma unroll
        for (int c = 0; c < 4; ++c) {
            #pragma unroll
            for (int kt = 0; kt < 2; ++kt) {
                bf16x8 kf = *(const bf16x8*)((const char*)LK
                              + (kt*16 + q) * 256 + ((c * 64 + g * 16) ^ sw16));
                st[0][kt] = __builtin_amdgcn_mfma_f32_16x16x32_bf16(kf, qf[0][c], st[0][kt], 0, 0, 0);
                st[1][kt] = __builtin_amdgcn_mfma_f32_16x16x32_bf16(kf, qf[1][c], st[1][kt], 0, 0, 0);
            }
        }
        __builtin_amdgcn_s_setprio(0);

        // ---- online softmax (log2 domain), defer-max ----
        float cm[2];
        #pragma unroll
        for (int n = 0; n < 2; ++n) {
            float c0 = -INFINITY;
            #pragma unroll
            for (int kt = 0; kt < 2; ++kt)
                #pragma unroll
                for (int r = 0; r < 4; ++r) c0 = fmaxf(c0, st[n][kt][r]);
            c0 = fmaxf(c0, __shfl_xor(c0, 16));
            c0 = fmaxf(c0, __shfl_xor(c0, 32));
            cm[n] = c0;
        }
        if (!__all((cm[0] <= mrun[0] + DEFER_THR) && (cm[1] <= mrun[1] + DEFER_THR))) {
            #pragma unroll
            for (int n = 0; n < 2; ++n) {
                float mnew = fmaxf(mrun[n], cm[n]);
                float sc = exp2f(mrun[n] - mnew);
                lsum[n] *= sc;
                #pragma unroll
                for (int dt = 0; dt < 8; ++dt) o[n][dt] *= sc;
                mrun[n] = mnew;
            }
        }

        // P in bf16: the K=16 B-fragment (k=g*4+j, col=q) IS the st layout ->
        // feeds PV directly, no LDS/shuffle redistribution.
        bf16x4 pkv[2][2];
        #pragma unroll
        for (int n = 0; n < 2; ++n) {
            float ps = 0.f;
            #pragma unroll
            for (int kt = 0; kt < 2; ++kt) {
                float p0 = exp2f(st[n][kt][0] - mrun[n]);
                float p1 = exp2f(st[n][kt][1] - mrun[n]);
                float p2 = exp2f(st[n][kt][2] - mrun[n]);
                float p3 = exp2f(st[n][kt][3] - mrun[n]);
                ps += (p0 + p1) + (p2 + p3);
                union { unsigned u[2]; bf16x4 v; } t;
                t.u[0] = pk2bf(p0, p1);
                t.u[1] = pk2bf(p2, p3);
                pkv[n][kt] = t.v;
            }
            ps += __shfl_xor(ps, 16);
            ps += __shfl_xor(ps, 32);
            lsum[n] += ps;
        }

        // ---- O^T += V^T * P^T via K=16 MFMA, A=V^T from LDS (b64), B=pkv regs ----
        __builtin_amdgcn_s_setprio(1);
        #pragma unroll
        for (int kt = 0; kt < 2; ++kt) {
            bf16x4 vfr[8];
            #pragma unroll
            for (int dt = 0; dt < 8; ++dt) {
                const int d = dt * 16 + q;
                vfr[dt] = *(const bf16x4*)((const char*)VT
                            + d * 64 + (((kt * 2 + gh) ^ vkey) << 4) + gb);
            }
            #pragma unroll
            for (int dt = 0; dt < 8; ++dt) {
                asm("v_mfma_f32_16x16x16_bf16 %0, %1, %2, %0"
                    : "+v"(o[0][dt]) : "v"(vfr[dt]), "v"(pkv[0][kt]));
                asm("v_mfma_f32_16x16x16_bf16 %0, %1, %2, %0"
                    : "+v"(o[1][dt]) : "v"(vfr[dt]), "v"(pkv[1][kt]));
            }
        }
        __builtin_amdgcn_s_setprio(0);

        if (ch + 1 < nch) {
            __syncthreads();           // all waves done reading LDS
            STAGE_WRITE();             // loads already retired under compute
            __syncthreads();
        }
    }

    // hazard insurance: asm MFMA writes o[], epilogue VALU reads it soon after
    asm volatile("s_nop 7\n\ts_nop 7");

    if constexpr (SPLIT) {
        float* opb = Opart + (size_t)pid * (QT * DH);
        #pragma unroll
        for (int n = 0; n < 2; ++n) {
            const int row = wv * 32 + n * 16 + q;
            float* op = opb + row * DH;
            #pragma unroll
            for (int dt = 0; dt < 8; ++dt) {
                float4 v;
                v.x = o[n][dt][0]; v.y = o[n][dt][1]; v.z = o[n][dt][2]; v.w = o[n][dt][3];
                *(float4*)(op + dt * 16 + g * 4) = v;
            }
            if (g == 0) {
                Ml[(size_t)pid * (QT * 2) + row * 2]     = mrun[n];
                Ml[(size_t)pid * (QT * 2) + row * 2 + 1] = lsum[n];
            }
        }
    } else {
        #pragma unroll
        for (int n = 0; n < 2; ++n) {
            const int qrow = qbase + wv * 32 + n * 16 + q;
            if (qrow >= SEQ) continue;
            const float inv = 1.f / (lsum[n] + 64.f * exp2f(-mrun[n]));
            float* op = Og + hoff + (size_t)qrow * DH;
            #pragma unroll
            for (int dt = 0; dt < 8; ++dt) {
                float4 v;
                v.x = o[n][dt][0] * inv; v.y = o[n][dt][1] * inv;
                v.z = o[n][dt][2] * inv; v.w = o[n][dt][3] * inv;
                *(float4*)(op + dt * 16 + g * 4) = v;
            }
        }
    }
    #undef STAGE_LOAD
    #undef STAGE_WRITE
}

// compile-time-S merge body (runtime-indexed local arrays would go to scratch)
template<int S>
__device__ __forceinline__ void merge_body(const float* __restrict__ Opart,
                                           const float* __restrict__ Ml,
                                           float* __restrict__ Og,
                                           int head, int qbase, int pbase,
                                           int row, int c4) {
    if (qbase + row >= SEQ) return;       // text tail
    float w[S], lv[S];
    float m = -INFINITY;
    #pragma unroll
    for (int s = 0; s < S; ++s) {
        w[s]  = Ml[(size_t)(pbase + s) * (QT * 2) + row * 2];
        lv[s] = Ml[(size_t)(pbase + s) * (QT * 2) + row * 2 + 1];
        m = fmaxf(m, w[s]);
    }
    float L = 64.f * exp2f(-m);           // 64 zero-pad keys (log2 domain)
    #pragma unroll
    for (int s = 0; s < S; ++s) { w[s] = exp2f(w[s] - m); L += w[s] * lv[s]; }
    const float inv = 1.f / L;

    float* op = Og + (size_t)head * SEQ * DH + (size_t)(qbase + row) * DH;
    #pragma unroll
    for (int half = 0; half < 2; ++half) {
        const int j = c4 + half * 16;
        float4 acc = make_float4(0.f, 0.f, 0.f, 0.f);
        #pragma unroll
        for (int s = 0; s < S; ++s) {
            const float4 p = *(const float4*)(Opart + (size_t)(pbase + s) * (QT * DH)
                                              + row * DH + j * 4);
            acc.x += w[s] * p.x; acc.y += w[s] * p.y;
            acc.z += w[s] * p.z; acc.w += w[s] * p.w;
        }
        float4 v; v.x = acc.x * inv; v.y = acc.y * inv; v.z = acc.z * inv; v.w = acc.w * inv;
        *(float4*)(op + j * 4) = v;
    }
}

// 8 blocks per q-tile (16-row slices): 2688 blocks -> not latency-bound
template<int TS, int IS>
__global__ __launch_bounds__(256) void sta_merge(const float* __restrict__ Opart,
                                                 const float* __restrict__ Ml,
                                                 float* __restrict__ Og) {
    const int bb = blockIdx.x;
    const int b = bb >> 3, slice = bb & 7;
    const int t = threadIdx.x;
    const int row = slice * 16 + (t >> 4);   // 0..127
    const int c4  = t & 15;                  // float4 column
    if (b < NHEADS * NTT) {
        merge_body<TS>(Opart, Ml, Og, b / NTT, IMG_LEN + (b % NTT) * QT,
                       b * TS, row, c4);
    } else {
        const int tile = b - NHEADS * NTT;
        merge_body<IS>(Opart, Ml, Og, tile / NIT, (tile % NIT) * QT,
                       NHEADS * NTT * TS + tile * IS, row, c4);
    }
}

extern "C" void kernel_launch(void* const* d_in, const int* in_sizes, int n_in,
                              void* d_out, int out_size, void* d_ws, size_t ws_size,
                              hipStream_t stream) {
    const float* Qg = (const float*)d_in[0];
    const float* Kg = (const float*)d_in[1];
    const float* Vg = (const float*)d_in[2];
    float* Og = (float*)d_out;
    float* ws = (float*)d_ws;

    const int nmerge = NHEADS * (NTT + NIT) * 8;   // 2688
    if (ws_size >= Geo<8, 4>::WS_FLOATS * sizeof(float)) {
        float* Opart = ws;
        float* Ml    = Opart + (size_t)Geo<8, 4>::NPID * QT * DH;
        hipLaunchKernelGGL((sta_attn<8, 4, true>), dim3(Geo<8, 4>::NPID), dim3(256), 0, stream,
                           Qg, Kg, Vg, Og, Opart, Ml);
        hipLaunchKernelGGL((sta_merge<8, 4>), dim3(nmerge), dim3(256), 0, stream,
                           Opart, Ml, Og);
    } else if (ws_size >= Geo<4, 2>::WS_FLOATS * sizeof(float)) {
        float* Opart = ws;
        float* Ml    = Opart + (size_t)Geo<4, 2>::NPID * QT * DH;
        hipLaunchKernelGGL((sta_attn<4, 2, true>), dim3(Geo<4, 2>::NPID), dim3(256), 0, stream,
                           Qg, Kg, Vg, Og, Opart, Ml);
        hipLaunchKernelGGL((sta_merge<4, 2>), dim3(nmerge), dim3(256), 0, stream,
                           Opart, Ml, Og);
    } else {
        hipLaunchKernelGGL((sta_attn<1, 1, false>), dim3(Geo<1, 1>::NPID), dim3(256), 0, stream,
                           Qg, Kg, Vg, Og, (float*)nullptr, (float*)nullptr);
    }
}

// Round 10
// 216.494 us; speedup vs baseline: 1.3083x; 1.0269x over previous
//
#include <hip/hip_runtime.h>

// ---- problem constants (from reference) ----
#define SEQ      10688      // IMG_LEN + TEXT_LEN
#define IMG_LEN  10368      // 18*24*24
#define TEXT_LEN 320
#define DH       128
#define NHEADS   4
#define SLAB     3456       // 6*24*24 tokens per time-slab
#define KVC      32         // kv chunk rows
#define QT       128        // q rows per block (4 waves x 32)
#define NIT      81         // image q-tiles per head
#define NTT      3          // text q-tiles per head (last tile half-valid)
#define NCH_TXT  334        // SEQ/KVC
#define NCH_IMG  118        // 108 slab chunks + 10 text chunks
#define SCALEL2E 0.12751744518924593f   // (1/sqrt(128)) * log2(e)
#define DEFER_THR 8.0f      // defer-max rescale threshold (T13)

typedef __bf16 bf16x8 __attribute__((ext_vector_type(8)));
typedef __bf16 bf16x4 __attribute__((ext_vector_type(4)));
typedef float  f32x4  __attribute__((ext_vector_type(4)));

__device__ __forceinline__ unsigned pk2bf(float a, float b) {
    union { __bf16 h[2]; unsigned u; } t;
    t.h[0] = (__bf16)a; t.h[1] = (__bf16)b;
    return t.u;
}

__device__ __forceinline__ void split_range(int total, int nsplit, int s, int& c0, int& n) {
    const int q = total / nsplit, r = total % nsplit;
    if (s < r) { c0 = s * (q + 1); n = q + 1; }
    else       { c0 = r * (q + 1) + (s - r) * q; n = q; }
}

template<int TS, int IS> struct Geo {
    static constexpr int NTXTB = NHEADS * NTT * TS;
    static constexpr int NIMGB = NHEADS * NIT * IS;
    static constexpr int NPID  = NTXTB + NIMGB;
    static constexpr size_t WS_FLOATS = (size_t)NPID * (QT * DH + QT * 2);
};

// NOTE: NO min-waves clamp! (256,4)->64 VGPR and (256,2)->128 VGPR both caused
// catastrophic scratch spills (rounds 3/5). Unconstrained -> ~104 VGPR (R9).
// Double-buffered LDS: ONE barrier/chunk; STAGE_WRITE(buf^1) overlaps compute(buf);
// vmcnt at the write waits on loads issued a full chunk earlier (fully retired).
template<int TS, int IS, bool SPLIT>
__global__ __launch_bounds__(256) void sta_attn(const float* __restrict__ Qg,
                                                const float* __restrict__ Kg,
                                                const float* __restrict__ Vg,
                                                float* __restrict__ Og,
                                                float* __restrict__ Opart,
                                                float* __restrict__ Ml) {
    using G = Geo<TS, IS>;
    // K: [kv][d] bf16 (32x128), 8-elem-granule XOR swizzle key (kv&7).
    // V^T: [d][kv] bf16 (128x32), 16B-granule XOR swizzle key ((d>>1)&3).
    // V staging: one d per lane (d=tid&127) -> write slot = 16(d&1)+4(gran^key):
    // 8 distinct slots per quarter-wave = 2-way = free (was 4-way with d-pairs).
    __shared__ __align__(16) unsigned short LK[2][KVC * DH];
    __shared__ __align__(16) unsigned short VT[2][DH * KVC];

    const int tid  = threadIdx.x;
    const int lane = tid & 63;
    const int wv   = tid >> 6;
    const int q    = lane & 15;       // MFMA col position (q for QK/PV outputs)
    const int g    = lane >> 4;       // lane group 0..3
    const int sw16 = (q & 7) << 4;    // K-read swizzle key (bytes)
    const int vkey = (q >> 1) & 3;    // V-read swizzle key (granule)
    const int gh   = g >> 1;
    const int gb   = (g & 1) * 8;     // byte sub-offset within V granule
    const int dv   = tid & 127;       // V staging: d index (one per lane)
    const int kvh  = tid >> 7;        // V staging: kv half (0/1)
    const int vkw  = (dv >> 1) & 3;   // V staging write key

    int b = blockIdx.x;
    int head, qbase, nch, ch0, kvb0, pid = 0;
    bool isText;
    if (b < G::NTXTB) {                        // text splits first (longest poles)
        int tb = b / TS, s = b % TS;
        head = tb / NTT; qbase = IMG_LEN + (tb % NTT) * QT;
        isText = true; kvb0 = 0;
        split_range(NCH_TXT, TS, s, ch0, nch);
        pid = b;
    } else {
        int bb = b - G::NTXTB; int tile = bb / IS, s = bb % IS;
        head = tile / NIT; qbase = (tile % NIT) * QT;
        isText = false; kvb0 = (qbase / SLAB) * SLAB;
        split_range(NCH_IMG, IS, s, ch0, nch);
        pid = G::NTXTB + bb;
    }

    const size_t hoff = (size_t)head * SEQ * DH;
    const float* Qh = Qg + hoff;
    const float* Kh = Kg + hoff;
    const float* Vh = Vg + hoff;

    // ---- Q fragments for 2 q-subtiles (B-operand layout), scale folded ----
    bf16x8 qf[2][4];
    #pragma unroll
    for (int n = 0; n < 2; ++n) {
        int qr = qbase + wv * 32 + n * 16 + q;
        if (qr > SEQ - 1) qr = SEQ - 1;        // text tail: clamp (discarded at store)
        const float* qp = Qh + (size_t)qr * DH;
        #pragma unroll
        for (int c = 0; c < 4; ++c) {
            float4 a = *(const float4*)(qp + c * 32 + g * 8);
            float4 d = *(const float4*)(qp + c * 32 + g * 8 + 4);
            union { unsigned u[4]; bf16x8 v; } t;
            t.u[0] = pk2bf(a.x * SCALEL2E, a.y * SCALEL2E);
            t.u[1] = pk2bf(a.z * SCALEL2E, a.w * SCALEL2E);
            t.u[2] = pk2bf(d.x * SCALEL2E, d.y * SCALEL2E);
            t.u[3] = pk2bf(d.z * SCALEL2E, d.w * SCALEL2E);
            qf[n][c] = t.v;
        }
    }

    f32x4 o[2][8];
    #pragma unroll
    for (int n = 0; n < 2; ++n)
        #pragma unroll
        for (int dt = 0; dt < 8; ++dt) o[n][dt] = f32x4{0.f, 0.f, 0.f, 0.f};
    float mrun[2] = {-INFINITY, -INFINITY};
    float lsum[2] = {0.f, 0.f};

    // persistent staging registers (32 VGPR): K 4xfloat4, V 16xfloat
    float4 kreg[4];
    float  vreg[16];

    auto kvaddr = [&](int gch) -> int {
        return isText ? gch * KVC
                      : (gch < 108 ? kvb0 + gch * KVC : IMG_LEN + (gch - 108) * KVC);
    };

    // issue-early: global loads only (latency flies under a full chunk of compute)
    #define STAGE_LOAD(KB)                                                       \
        {   const int _kb = (KB);                                                \
            _Pragma("unroll")                                                    \
            for (int s = 0; s < 4; ++s) {                                        \
                int idx = tid + (s << 8);                                        \
                kreg[s] = *(const float4*)(Kh + (size_t)(_kb + (idx >> 5)) * DH  \
                                           + (idx & 31) * 4);                    \
            }                                                                    \
            const float* vpp = Vh + (size_t)(_kb + kvh * 16) * DH + dv;          \
            _Pragma("unroll")                                                    \
            for (int j = 0; j < 16; ++j) vreg[j] = vpp[j * DH];                  \
        }

    // write-late into buffer BUF (the one NOT being computed on this chunk)
    #define STAGE_WRITE(BUF)                                                     \
        {   const int _bf = (BUF);                                               \
            _Pragma("unroll")                                                    \
            for (int s = 0; s < 4; ++s) {                                        \
                int idx = tid + (s << 8);                                        \
                int kv = idx >> 5, dq = idx & 31;                                \
                uint2 u; u.x = pk2bf(kreg[s].x, kreg[s].y);                      \
                         u.y = pk2bf(kreg[s].z, kreg[s].w);                      \
                *(uint2*)&LK[_bf][kv * DH + ((dq * 4) ^ ((kv & 7) << 3))] = u;   \
            }                                                                    \
            _Pragma("unroll")                                                    \
            for (int j2 = 0; j2 < 2; ++j2) {                                     \
                uint4 u;                                                         \
                u.x = pk2bf(vreg[j2*8+0], vreg[j2*8+1]);                         \
                u.y = pk2bf(vreg[j2*8+2], vreg[j2*8+3]);                         \
                u.z = pk2bf(vreg[j2*8+4], vreg[j2*8+5]);                         \
                u.w = pk2bf(vreg[j2*8+6], vreg[j2*8+7]);                         \
                *(uint4*)&VT[_bf][dv * KVC + (((kvh*2 + j2) ^ vkw) * 8)] = u;    \
            }                                                                    \
        }

    STAGE_LOAD(kvaddr(ch0));
    STAGE_WRITE(0);
    if (nch > 1) STAGE_LOAD(kvaddr(ch0 + 1));
    __syncthreads();

    for (int ch = 0; ch < nch; ++ch) {
        const int buf = ch & 1;
        if (ch + 1 < nch) {
            STAGE_WRITE(buf ^ 1);          // overlaps this chunk's compute
            if (ch + 2 < nch) STAGE_LOAD(kvaddr(ch0 + ch + 2));
        }

        // ---- S^T = K * Q^T : st[n][kt][r] = S[kv=kt*16+g*4+r][q=n*16+q'] ----
        f32x4 st[2][2];
        #pragma unroll
        for (int n = 0; n < 2; ++n)
            #pragma unroll
            for (int kt = 0; kt < 2; ++kt) st[n][kt] = f32x4{0.f, 0.f, 0.f, 0.f};
        __builtin_amdgcn_s_setprio(1);
        #pragma unroll
        for (int c = 0; c < 4; ++c) {
            #pragma unroll
            for (int kt = 0; kt < 2; ++kt) {
                bf16x8 kf = *(const bf16x8*)((const char*)&LK[buf][0]
                              + (kt*16 + q) * 256 + ((c * 64 + g * 16) ^ sw16));
                st[0][kt] = __builtin_amdgcn_mfma_f32_16x16x32_bf16(kf, qf[0][c], st[0][kt], 0, 0, 0);
                st[1][kt] = __builtin_amdgcn_mfma_f32_16x16x32_bf16(kf, qf[1][c], st[1][kt], 0, 0, 0);
            }
        }
        __builtin_amdgcn_s_setprio(0);

        // ---- online softmax (log2 domain), defer-max ----
        float cm[2];
        #pragma unroll
        for (int n = 0; n < 2; ++n) {
            float c0 = -INFINITY;
            #pragma unroll
            for (int kt = 0; kt < 2; ++kt)
                #pragma unroll
                for (int r = 0; r < 4; ++r) c0 = fmaxf(c0, st[n][kt][r]);
            c0 = fmaxf(c0, __shfl_xor(c0, 16));
            c0 = fmaxf(c0, __shfl_xor(c0, 32));
            cm[n] = c0;
        }
        if (!__all((cm[0] <= mrun[0] + DEFER_THR) && (cm[1] <= mrun[1] + DEFER_THR))) {
            #pragma unroll
            for (int n = 0; n < 2; ++n) {
                float mnew = fmaxf(mrun[n], cm[n]);
                float sc = exp2f(mrun[n] - mnew);
                lsum[n] *= sc;
                #pragma unroll
                for (int dt = 0; dt < 8; ++dt) o[n][dt] *= sc;
                mrun[n] = mnew;
            }
        }

        // P in bf16: the K=16 B-fragment (k=g*4+j, col=q) IS the st layout ->
        // feeds PV directly, no LDS/shuffle redistribution.
        bf16x4 pkv[2][2];
        #pragma unroll
        for (int n = 0; n < 2; ++n) {
            float ps = 0.f;
            #pragma unroll
            for (int kt = 0; kt < 2; ++kt) {
                float p0 = exp2f(st[n][kt][0] - mrun[n]);
                float p1 = exp2f(st[n][kt][1] - mrun[n]);
                float p2 = exp2f(st[n][kt][2] - mrun[n]);
                float p3 = exp2f(st[n][kt][3] - mrun[n]);
                ps += (p0 + p1) + (p2 + p3);
                union { unsigned u[2]; bf16x4 v; } t;
                t.u[0] = pk2bf(p0, p1);
                t.u[1] = pk2bf(p2, p3);
                pkv[n][kt] = t.v;
            }
            ps += __shfl_xor(ps, 16);
            ps += __shfl_xor(ps, 32);
            lsum[n] += ps;
        }

        // ---- O^T += V^T * P^T via K=16 MFMA, A=V^T from LDS (b64), B=pkv regs ----
        __builtin_amdgcn_s_setprio(1);
        #pragma unroll
        for (int kt = 0; kt < 2; ++kt) {
            bf16x4 vfr[8];
            #pragma unroll
            for (int dt = 0; dt < 8; ++dt) {
                const int d = dt * 16 + q;
                vfr[dt] = *(const bf16x4*)((const char*)&VT[buf][0]
                            + d * 64 + (((kt * 2 + gh) ^ vkey) << 4) + gb);
            }
            #pragma unroll
            for (int dt = 0; dt < 8; ++dt) {
                asm("v_mfma_f32_16x16x16_bf16 %0, %1, %2, %0"
                    : "+v"(o[0][dt]) : "v"(vfr[dt]), "v"(pkv[0][kt]));
                asm("v_mfma_f32_16x16x16_bf16 %0, %1, %2, %0"
                    : "+v"(o[1][dt]) : "v"(vfr[dt]), "v"(pkv[1][kt]));
            }
        }
        __builtin_amdgcn_s_setprio(0);

        if (ch + 1 < nch) __syncthreads();     // single barrier per chunk
    }

    // hazard insurance: asm MFMA writes o[], epilogue VALU reads it soon after
    asm volatile("s_nop 7\n\ts_nop 7");

    if constexpr (SPLIT) {
        float* opb = Opart + (size_t)pid * (QT * DH);
        #pragma unroll
        for (int n = 0; n < 2; ++n) {
            const int row = wv * 32 + n * 16 + q;
            float* op = opb + row * DH;
            #pragma unroll
            for (int dt = 0; dt < 8; ++dt) {
                float4 v;
                v.x = o[n][dt][0]; v.y = o[n][dt][1]; v.z = o[n][dt][2]; v.w = o[n][dt][3];
                *(float4*)(op + dt * 16 + g * 4) = v;
            }
            if (g == 0) {
                Ml[(size_t)pid * (QT * 2) + row * 2]     = mrun[n];
                Ml[(size_t)pid * (QT * 2) + row * 2 + 1] = lsum[n];
            }
        }
    } else {
        #pragma unroll
        for (int n = 0; n < 2; ++n) {
            const int qrow = qbase + wv * 32 + n * 16 + q;
            if (qrow >= SEQ) continue;
            const float inv = 1.f / (lsum[n] + 64.f * exp2f(-mrun[n]));
            float* op = Og + hoff + (size_t)qrow * DH;
            #pragma unroll
            for (int dt = 0; dt < 8; ++dt) {
                float4 v;
                v.x = o[n][dt][0] * inv; v.y = o[n][dt][1] * inv;
                v.z = o[n][dt][2] * inv; v.w = o[n][dt][3] * inv;
                *(float4*)(op + dt * 16 + g * 4) = v;
            }
        }
    }
    #undef STAGE_LOAD
    #undef STAGE_WRITE
}

// compile-time-S merge body (runtime-indexed local arrays would go to scratch)
template<int S>
__device__ __forceinline__ void merge_body(const float* __restrict__ Opart,
                                           const float* __restrict__ Ml,
                                           float* __restrict__ Og,
                                           int head, int qbase, int pbase,
                                           int row, int c4) {
    if (qbase + row >= SEQ) return;       // text tail
    float w[S], lv[S];
    float m = -INFINITY;
    #pragma unroll
    for (int s = 0; s < S; ++s) {
        w[s]  = Ml[(size_t)(pbase + s) * (QT * 2) + row * 2];
        lv[s] = Ml[(size_t)(pbase + s) * (QT * 2) + row * 2 + 1];
        m = fmaxf(m, w[s]);
    }
    float L = 64.f * exp2f(-m);           // 64 zero-pad keys (log2 domain)
    #pragma unroll
    for (int s = 0; s < S; ++s) { w[s] = exp2f(w[s] - m); L += w[s] * lv[s]; }
    const float inv = 1.f / L;

    float* op = Og + (size_t)head * SEQ * DH + (size_t)(qbase + row) * DH;
    #pragma unroll
    for (int half = 0; half < 2; ++half) {
        const int j = c4 + half * 16;
        float4 acc = make_float4(0.f, 0.f, 0.f, 0.f);
        #pragma unroll
        for (int s = 0; s < S; ++s) {
            const float4 p = *(const float4*)(Opart + (size_t)(pbase + s) * (QT * DH)
                                              + row * DH + j * 4);
            acc.x += w[s] * p.x; acc.y += w[s] * p.y;
            acc.z += w[s] * p.z; acc.w += w[s] * p.w;
        }
        float4 v; v.x = acc.x * inv; v.y = acc.y * inv; v.z = acc.z * inv; v.w = acc.w * inv;
        *(float4*)(op + j * 4) = v;
    }
}

// 8 blocks per q-tile (16-row slices): 2688 blocks -> not latency-bound
template<int TS, int IS>
__global__ __launch_bounds__(256) void sta_merge(const float* __restrict__ Opart,
                                                 const float* __restrict__ Ml,
                                                 float* __restrict__ Og) {
    const int bb = blockIdx.x;
    const int b = bb >> 3, slice = bb & 7;
    const int t = threadIdx.x;
    const int row = slice * 16 + (t >> 4);   // 0..127
    const int c4  = t & 15;                  // float4 column
    if (b < NHEADS * NTT) {
        merge_body<TS>(Opart, Ml, Og, b / NTT, IMG_LEN + (b % NTT) * QT,
                       b * TS, row, c4);
    } else {
        const int tile = b - NHEADS * NTT;
        merge_body<IS>(Opart, Ml, Og, tile / NIT, (tile % NIT) * QT,
                       NHEADS * NTT * TS + tile * IS, row, c4);
    }
}

extern "C" void kernel_launch(void* const* d_in, const int* in_sizes, int n_in,
                              void* d_out, int out_size, void* d_ws, size_t ws_size,
                              hipStream_t stream) {
    const float* Qg = (const float*)d_in[0];
    const float* Kg = (const float*)d_in[1];
    const float* Vg = (const float*)d_in[2];
    float* Og = (float*)d_out;
    float* ws = (float*)d_ws;

    const int nmerge = NHEADS * (NTT + NIT) * 8;   // 2688
    if (ws_size >= Geo<8, 4>::WS_FLOATS * sizeof(float)) {
        float* Opart = ws;
        float* Ml    = Opart + (size_t)Geo<8, 4>::NPID * QT * DH;
        hipLaunchKernelGGL((sta_attn<8, 4, true>), dim3(Geo<8, 4>::NPID), dim3(256), 0, stream,
                           Qg, Kg, Vg, Og, Opart, Ml);
        hipLaunchKernelGGL((sta_merge<8, 4>), dim3(nmerge), dim3(256), 0, stream,
                           Opart, Ml, Og);
    } else if (ws_size >= Geo<4, 2>::WS_FLOATS * sizeof(float)) {
        float* Opart = ws;
        float* Ml    = Opart + (size_t)Geo<4, 2>::NPID * QT * DH;
        hipLaunchKernelGGL((sta_attn<4, 2, true>), dim3(Geo<4, 2>::NPID), dim3(256), 0, stream,
                           Qg, Kg, Vg, Og, Opart, Ml);
        hipLaunchKernelGGL((sta_merge<4, 2>), dim3(nmerge), dim3(256), 0, stream,
                           Opart, Ml, Og);
    } else {
        hipLaunchKernelGGL((sta_attn<1, 1, false>), dim3(Geo<1, 1>::NPID), dim3(256), 0, stream,
                           Qg, Kg, Vg, Og, (float*)nullptr, (float*)nullptr);
    }
}

// Round 11
// 211.095 us; speedup vs baseline: 1.3418x; 1.0256x over previous
//
#include <hip/hip_runtime.h>

// ---- problem constants (from reference) ----
#define SEQ      10688      // IMG_LEN + TEXT_LEN
#define IMG_LEN  10368      // 18*24*24
#define TEXT_LEN 320
#define DH       128
#define NHEADS   4
#define SLAB     3456       // 6*24*24 tokens per time-slab
#define KVC      32         // kv chunk rows
#define QT       128        // q rows per block (4 waves x 32)
#define NIT      81         // image q-tiles per head
#define NTT      3          // text q-tiles per head (last tile half-valid)
#define NCH_TXT  334        // SEQ/KVC
#define NCH_IMG  118        // 108 slab chunks + 10 text chunks
#define SCALEL2E 0.12751744518924593f   // (1/sqrt(128)) * log2(e)
#define DEFER_THR 8.0f      // defer-max rescale threshold (T13)

typedef __bf16 bf16x8 __attribute__((ext_vector_type(8)));
typedef __bf16 bf16x4 __attribute__((ext_vector_type(4)));
typedef float  f32x4  __attribute__((ext_vector_type(4)));

__device__ __forceinline__ unsigned pk2bf(float a, float b) {
    union { __bf16 h[2]; unsigned u; } t;
    t.h[0] = (__bf16)a; t.h[1] = (__bf16)b;
    return t.u;
}

__device__ __forceinline__ void gload_lds16(const void* g, void* l) {
    __builtin_amdgcn_global_load_lds(
        (const __attribute__((address_space(1))) void*)g,
        (__attribute__((address_space(3))) void*)l, 16, 0, 0);
}

__device__ __forceinline__ void split_range(int total, int nsplit, int s, int& c0, int& n) {
    const int q = total / nsplit, r = total % nsplit;
    if (s < r) { c0 = s * (q + 1); n = q + 1; }
    else       { c0 = r * (q + 1) + (s - r) * q; n = q; }
}

template<int TS, int IS> struct Geo {
    static constexpr int NTXTB = NHEADS * NTT * TS;
    static constexpr int NIMGB = NHEADS * NIT * IS;
    static constexpr int NPID  = NTXTB + NIMGB;
    static constexpr size_t WS_FLOATS = (size_t)NPID * (QT * DH + QT * 2);
};
#define KB_BYTES ((size_t)NHEADS * SEQ * DH * 2)   // bf16 K (or V^T) array size

// ---- pre-pass: K -> bf16 (same layout); V -> bf16 TRANSPOSED [head][d][kv] ----
// Conversion cost paid once instead of ~30x (27 img tiles + text splits per chunk).
__global__ __launch_bounds__(256) void sta_prep(const float* __restrict__ Kg,
                                                const float* __restrict__ Vg,
                                                unsigned short* __restrict__ Kb,
                                                unsigned short* __restrict__ VTb) {
    __shared__ float T[64][65];
    const int b = blockIdx.x;
    if (b < 2672) {                      // K convert: 4*SEQ*128 elems, 8/thread
        const size_t i = ((size_t)b * 256 + threadIdx.x) * 8;
        float4 a = *(const float4*)(Kg + i);
        float4 c = *(const float4*)(Kg + i + 4);
        uint4 u; u.x = pk2bf(a.x, a.y); u.y = pk2bf(a.z, a.w);
                 u.z = pk2bf(c.x, c.y); u.w = pk2bf(c.z, c.w);
        *(uint4*)(Kb + i) = u;
    } else {                             // V transpose: 64kv x 64d LDS tile
        const int bb = b - 2672;
        const int dt = bb & 1, kvt = (bb >> 1) % 167, h = (bb >> 1) / 167;
        const float* src = Vg + ((size_t)h * SEQ + kvt * 64) * DH + dt * 64;
        const int t = threadIdx.x;
        const int col = t & 63, r4 = t >> 6;
        #pragma unroll
        for (int i = 0; i < 16; ++i) {
            const int row = i * 4 + r4;
            T[row][col] = src[(size_t)row * DH + col];
        }
        __syncthreads();
        unsigned short* dst = VTb + ((size_t)h * DH + dt * 64) * SEQ + kvt * 64;
        const int kp = t & 31, dq = t >> 5;
        #pragma unroll
        for (int i = 0; i < 8; ++i) {
            const int dd = i * 8 + dq;
            unsigned u = pk2bf(T[kp * 2][dd], T[kp * 2 + 1][dd]);
            *(unsigned*)(dst + (size_t)dd * SEQ + kp * 2) = u;
        }
    }
}

// NOTE: NO min-waves clamp! (256,4)->64 VGPR and (256,2)->128 VGPR both caused
// catastrophic scratch spills (rounds 3/5).
// Staging = 4 global_load_lds per wave per chunk (DMA; linear LDS dest =
// conflict-free writes). XOR swizzle applied on the GLOBAL source address
// (rule #21); read-side formulas identical to R10's verified ones.
template<int TS, int IS, bool SPLIT>
__global__ __launch_bounds__(256) void sta_attn(const float* __restrict__ Qg,
                                                const unsigned short* __restrict__ Kb,
                                                const unsigned short* __restrict__ VTb,
                                                float* __restrict__ Og,
                                                float* __restrict__ Opart,
                                                float* __restrict__ Ml) {
    using G = Geo<TS, IS>;
    // K: [kv][d] bf16 (32x128), 16B-granule XOR key (kv&7) (granule idx 0..15).
    // V^T: [d][kv] bf16 (128x32), 16B-granule XOR key ((d>>1)&3) (granule 0..3).
    __shared__ __align__(16) unsigned short LK[2][KVC * DH];
    __shared__ __align__(16) unsigned short VT[2][DH * KVC];

    const int tid  = threadIdx.x;
    const int lane = tid & 63;
    const int wv   = tid >> 6;
    const int q    = lane & 15;       // MFMA col position (q for QK/PV outputs)
    const int g    = lane >> 4;       // lane group 0..3
    const int sw16 = (q & 7) << 4;    // K-read swizzle key (bytes)
    const int vkey = (q >> 1) & 3;    // V-read swizzle key (granule)
    const int gh   = g >> 1;
    const int gb   = (g & 1) * 8;     // byte sub-offset within V granule

    // per-lane DMA source offsets (bytes), inverse-swizzled (chunk-invariant)
    int koff[2], voff[2];
    #pragma unroll
    for (int j = 0; j < 2; ++j) {
        const int idx = wv * 128 + j * 64 + lane;            // linear 16B granule
        koff[j] = (idx >> 4) * 256 + (((idx & 15) ^ ((idx >> 4) & 7)) << 4);
        voff[j] = (idx >> 2) * (SEQ * 2) + (((idx & 3) ^ ((idx >> 3) & 3)) << 4);
    }

    int b = blockIdx.x;
    int head, qbase, nch, ch0, kvb0, pid = 0;
    bool isText;
    if (b < G::NTXTB) {                        // text splits first (longest poles)
        int tb = b / TS, s = b % TS;
        head = tb / NTT; qbase = IMG_LEN + (tb % NTT) * QT;
        isText = true; kvb0 = 0;
        split_range(NCH_TXT, TS, s, ch0, nch);
        pid = b;
    } else {
        int bb = b - G::NTXTB; int tile = bb / IS, s = bb % IS;
        head = tile / NIT; qbase = (tile % NIT) * QT;
        isText = false; kvb0 = (qbase / SLAB) * SLAB;
        split_range(NCH_IMG, IS, s, ch0, nch);
        pid = G::NTXTB + bb;
    }

    const size_t hoff = (size_t)head * SEQ * DH;
    const float* Qh = Qg + hoff;
    const char* khb = (const char*)Kb  + hoff * 2;            // kv-row stride 256B
    const char* vhb = (const char*)VTb + hoff * 2;            // d-row stride SEQ*2

    // ---- Q fragments for 2 q-subtiles (B-operand layout), scale folded ----
    bf16x8 qf[2][4];
    #pragma unroll
    for (int n = 0; n < 2; ++n) {
        int qr = qbase + wv * 32 + n * 16 + q;
        if (qr > SEQ - 1) qr = SEQ - 1;        // text tail: clamp (discarded at store)
        const float* qp = Qh + (size_t)qr * DH;
        #pragma unroll
        for (int c = 0; c < 4; ++c) {
            float4 a = *(const float4*)(qp + c * 32 + g * 8);
            float4 d = *(const float4*)(qp + c * 32 + g * 8 + 4);
            union { unsigned u[4]; bf16x8 v; } t;
            t.u[0] = pk2bf(a.x * SCALEL2E, a.y * SCALEL2E);
            t.u[1] = pk2bf(a.z * SCALEL2E, a.w * SCALEL2E);
            t.u[2] = pk2bf(d.x * SCALEL2E, d.y * SCALEL2E);
            t.u[3] = pk2bf(d.z * SCALEL2E, d.w * SCALEL2E);
            qf[n][c] = t.v;
        }
    }

    f32x4 o[2][8];
    #pragma unroll
    for (int n = 0; n < 2; ++n)
        #pragma unroll
        for (int dt = 0; dt < 8; ++dt) o[n][dt] = f32x4{0.f, 0.f, 0.f, 0.f};
    float mrun[2] = {-INFINITY, -INFINITY};
    float lsum[2] = {0.f, 0.f};

    auto kvaddr = [&](int gch) -> int {
        return isText ? gch * KVC
                      : (gch < 108 ? kvb0 + gch * KVC : IMG_LEN + (gch - 108) * KVC);
    };

    // 4 DMA issues per wave per chunk; LDS writes linear (conflict-free)
    #define STAGE_DMA(BUF, KB)                                                   \
        {   const char* ks = khb + (size_t)(KB) * 256;                           \
            const char* vs = vhb + (size_t)(KB) * 2;                             \
            gload_lds16(ks + koff[0], &LK[BUF][wv * 1024]);                      \
            gload_lds16(ks + koff[1], &LK[BUF][wv * 1024 + 512]);                \
            gload_lds16(vs + voff[0], &VT[BUF][wv * 1024]);                      \
            gload_lds16(vs + voff[1], &VT[BUF][wv * 1024 + 512]);                \
        }

    STAGE_DMA(0, kvaddr(ch0));
    __syncthreads();                       // drains DMA (vmcnt) + syncs

    for (int ch = 0; ch < nch; ++ch) {
        const int buf = ch & 1;
        // issue next chunk's DMA now; retires under this chunk's compute
        if (ch + 1 < nch) STAGE_DMA(buf ^ 1, kvaddr(ch0 + ch + 1));

        // ---- S^T = K * Q^T : st[n][kt][r] = S[kv=kt*16+g*4+r][q=n*16+q'] ----
        f32x4 st[2][2];
        #pragma unroll
        for (int n = 0; n < 2; ++n)
            #pragma unroll
            for (int kt = 0; kt < 2; ++kt) st[n][kt] = f32x4{0.f, 0.f, 0.f, 0.f};
        __builtin_amdgcn_s_setprio(1);
        #pragma unroll
        for (int c = 0; c < 4; ++c) {
            #pragma unroll
            for (int kt = 0; kt < 2; ++kt) {
                bf16x8 kf = *(const bf16x8*)((const char*)&LK[buf][0]
                              + (kt*16 + q) * 256 + ((c * 64 + g * 16) ^ sw16));
                st[0][kt] = __builtin_amdgcn_mfma_f32_16x16x32_bf16(kf, qf[0][c], st[0][kt], 0, 0, 0);
                st[1][kt] = __builtin_amdgcn_mfma_f32_16x16x32_bf16(kf, qf[1][c], st[1][kt], 0, 0, 0);
            }
        }
        __builtin_amdgcn_s_setprio(0);

        // ---- online softmax (log2 domain), defer-max ----
        float cm[2];
        #pragma unroll
        for (int n = 0; n < 2; ++n) {
            float a0 = fmaxf(fmaxf(st[n][0][0], st[n][0][1]), fmaxf(st[n][0][2], st[n][0][3]));
            float a1 = fmaxf(fmaxf(st[n][1][0], st[n][1][1]), fmaxf(st[n][1][2], st[n][1][3]));
            float c0 = fmaxf(a0, a1);
            c0 = fmaxf(c0, __shfl_xor(c0, 16));
            c0 = fmaxf(c0, __shfl_xor(c0, 32));
            cm[n] = c0;
        }
        if (!__all((cm[0] <= mrun[0] + DEFER_THR) && (cm[1] <= mrun[1] + DEFER_THR))) {
            #pragma unroll
            for (int n = 0; n < 2; ++n) {
                float mnew = fmaxf(mrun[n], cm[n]);
                float sc = exp2f(mrun[n] - mnew);
                lsum[n] *= sc;
                #pragma unroll
                for (int dt = 0; dt < 8; ++dt) o[n][dt] *= sc;
                mrun[n] = mnew;
            }
        }

        // P in bf16: the K=16 B-fragment (k=g*4+j, col=q) IS the st layout ->
        // feeds PV directly, no LDS/shuffle redistribution.
        bf16x4 pkv[2][2];
        #pragma unroll
        for (int n = 0; n < 2; ++n) {
            float ps = 0.f;
            #pragma unroll
            for (int kt = 0; kt < 2; ++kt) {
                float p0 = exp2f(st[n][kt][0] - mrun[n]);
                float p1 = exp2f(st[n][kt][1] - mrun[n]);
                float p2 = exp2f(st[n][kt][2] - mrun[n]);
                float p3 = exp2f(st[n][kt][3] - mrun[n]);
                ps += (p0 + p1) + (p2 + p3);
                union { unsigned u[2]; bf16x4 v; } t;
                t.u[0] = pk2bf(p0, p1);
                t.u[1] = pk2bf(p2, p3);
                pkv[n][kt] = t.v;
            }
            ps += __shfl_xor(ps, 16);
            ps += __shfl_xor(ps, 32);
            lsum[n] += ps;
        }

        // ---- O^T += V^T * P^T via K=16 MFMA, A=V^T from LDS (b64), B=pkv regs ----
        __builtin_amdgcn_s_setprio(1);
        #pragma unroll
        for (int kt = 0; kt < 2; ++kt) {
            bf16x4 vfr[8];
            #pragma unroll
            for (int dt = 0; dt < 8; ++dt) {
                const int d = dt * 16 + q;
                vfr[dt] = *(const bf16x4*)((const char*)&VT[buf][0]
                            + d * 64 + (((kt * 2 + gh) ^ vkey) << 4) + gb);
            }
            #pragma unroll
            for (int dt = 0; dt < 8; ++dt) {
                asm("v_mfma_f32_16x16x16_bf16 %0, %1, %2, %0"
                    : "+v"(o[0][dt]) : "v"(vfr[dt]), "v"(pkv[0][kt]));
                asm("v_mfma_f32_16x16x16_bf16 %0, %1, %2, %0"
                    : "+v"(o[1][dt]) : "v"(vfr[dt]), "v"(pkv[1][kt]));
            }
        }
        __builtin_amdgcn_s_setprio(0);

        if (ch + 1 < nch) __syncthreads();     // drains DMA + syncs readers
    }

    // hazard insurance: asm MFMA writes o[], epilogue VALU reads it soon after
    asm volatile("s_nop 7\n\ts_nop 7");

    if constexpr (SPLIT) {
        float* opb = Opart + (size_t)pid * (QT * DH);
        #pragma unroll
        for (int n = 0; n < 2; ++n) {
            const int row = wv * 32 + n * 16 + q;
            float* op = opb + row * DH;
            #pragma unroll
            for (int dt = 0; dt < 8; ++dt) {
                float4 v;
                v.x = o[n][dt][0]; v.y = o[n][dt][1]; v.z = o[n][dt][2]; v.w = o[n][dt][3];
                *(float4*)(op + dt * 16 + g * 4) = v;
            }
            if (g == 0) {
                Ml[(size_t)pid * (QT * 2) + row * 2]     = mrun[n];
                Ml[(size_t)pid * (QT * 2) + row * 2 + 1] = lsum[n];
            }
        }
    } else {
        #pragma unroll
        for (int n = 0; n < 2; ++n) {
            const int qrow = qbase + wv * 32 + n * 16 + q;
            if (qrow >= SEQ) continue;
            const float inv = 1.f / (lsum[n] + 64.f * exp2f(-mrun[n]));
            float* op = Og + hoff + (size_t)qrow * DH;
            #pragma unroll
            for (int dt = 0; dt < 8; ++dt) {
                float4 v;
                v.x = o[n][dt][0] * inv; v.y = o[n][dt][1] * inv;
                v.z = o[n][dt][2] * inv; v.w = o[n][dt][3] * inv;
                *(float4*)(op + dt * 16 + g * 4) = v;
            }
        }
    }
    #undef STAGE_DMA
}

// compile-time-S merge body (runtime-indexed local arrays would go to scratch)
template<int S>
__device__ __forceinline__ void merge_body(const float* __restrict__ Opart,
                                           const float* __restrict__ Ml,
                                           float* __restrict__ Og,
                                           int head, int qbase, int pbase,
                                           int row, int c4) {
    if (qbase + row >= SEQ) return;       // text tail
    float w[S], lv[S];
    float m = -INFINITY;
    #pragma unroll
    for (int s = 0; s < S; ++s) {
        w[s]  = Ml[(size_t)(pbase + s) * (QT * 2) + row * 2];
        lv[s] = Ml[(size_t)(pbase + s) * (QT * 2) + row * 2 + 1];
        m = fmaxf(m, w[s]);
    }
    float L = 64.f * exp2f(-m);           // 64 zero-pad keys (log2 domain)
    #pragma unroll
    for (int s = 0; s < S; ++s) { w[s] = exp2f(w[s] - m); L += w[s] * lv[s]; }
    const float inv = 1.f / L;

    float* op = Og + (size_t)head * SEQ * DH + (size_t)(qbase + row) * DH;
    #pragma unroll
    for (int half = 0; half < 2; ++half) {
        const int j = c4 + half * 16;
        float4 acc = make_float4(0.f, 0.f, 0.f, 0.f);
        #pragma unroll
        for (int s = 0; s < S; ++s) {
            const float4 p = *(const float4*)(Opart + (size_t)(pbase + s) * (QT * DH)
                                              + row * DH + j * 4);
            acc.x += w[s] * p.x; acc.y += w[s] * p.y;
            acc.z += w[s] * p.z; acc.w += w[s] * p.w;
        }
        float4 v; v.x = acc.x * inv; v.y = acc.y * inv; v.z = acc.z * inv; v.w = acc.w * inv;
        *(float4*)(op + j * 4) = v;
    }
}

// 8 blocks per q-tile (16-row slices): 2688 blocks -> not latency-bound
template<int TS, int IS>
__global__ __launch_bounds__(256) void sta_merge(const float* __restrict__ Opart,
                                                 const float* __restrict__ Ml,
                                                 float* __restrict__ Og) {
    const int bb = blockIdx.x;
    const int b = bb >> 3, slice = bb & 7;
    const int t = threadIdx.x;
    const int row = slice * 16 + (t >> 4);   // 0..127
    const int c4  = t & 15;                  // float4 column
    if (b < NHEADS * NTT) {
        merge_body<TS>(Opart, Ml, Og, b / NTT, IMG_LEN + (b % NTT) * QT,
                       b * TS, row, c4);
    } else {
        const int tile = b - NHEADS * NTT;
        merge_body<IS>(Opart, Ml, Og, tile / NIT, (tile % NIT) * QT,
                       NHEADS * NTT * TS + tile * IS, row, c4);
    }
}

extern "C" void kernel_launch(void* const* d_in, const int* in_sizes, int n_in,
                              void* d_out, int out_size, void* d_ws, size_t ws_size,
                              hipStream_t stream) {
    const float* Qg = (const float*)d_in[0];
    const float* Kg = (const float*)d_in[1];
    const float* Vg = (const float*)d_in[2];
    float* Og = (float*)d_out;
    char* wsb = (char*)d_ws;

    unsigned short* Kb  = (unsigned short*)wsb;
    unsigned short* VTb = (unsigned short*)(wsb + KB_BYTES);
    float* Opart = (float*)(wsb + 2 * KB_BYTES);
    const int nprep  = 2672 + NHEADS * 2 * 167;    // 4008
    const int nmerge = NHEADS * (NTT + NIT) * 8;   // 2688

    if (ws_size >= 2 * KB_BYTES + Geo<8, 4>::WS_FLOATS * sizeof(float)) {
        float* Ml = Opart + (size_t)Geo<8, 4>::NPID * QT * DH;
        hipLaunchKernelGGL(sta_prep, dim3(nprep), dim3(256), 0, stream, Kg, Vg, Kb, VTb);
        hipLaunchKernelGGL((sta_attn<8, 4, true>), dim3(Geo<8, 4>::NPID), dim3(256), 0, stream,
                           Qg, Kb, VTb, Og, Opart, Ml);
        hipLaunchKernelGGL((sta_merge<8, 4>), dim3(nmerge), dim3(256), 0, stream,
                           Opart, Ml, Og);
    } else if (ws_size >= 2 * KB_BYTES + Geo<4, 2>::WS_FLOATS * sizeof(float)) {
        float* Ml = Opart + (size_t)Geo<4, 2>::NPID * QT * DH;
        hipLaunchKernelGGL(sta_prep, dim3(nprep), dim3(256), 0, stream, Kg, Vg, Kb, VTb);
        hipLaunchKernelGGL((sta_attn<4, 2, true>), dim3(Geo<4, 2>::NPID), dim3(256), 0, stream,
                           Qg, Kb, VTb, Og, Opart, Ml);
        hipLaunchKernelGGL((sta_merge<4, 2>), dim3(nmerge), dim3(256), 0, stream,
                           Opart, Ml, Og);
    } else {
        // last-resort: unsplit, still pre-pass (needs ~22MB; proven ws >= 93MB)
        hipLaunchKernelGGL(sta_prep, dim3(nprep), dim3(256), 0, stream, Kg, Vg, Kb, VTb);
        hipLaunchKernelGGL((sta_attn<1, 1, false>), dim3(Geo<1, 1>::NPID), dim3(256), 0, stream,
                           Qg, Kb, VTb, Og, (float*)nullptr, (float*)nullptr);
    }
}